// Round 16
// baseline (180.017 us; speedup 1.0000x reference)
//
#include <hip/hip_runtime.h>

typedef __attribute__((ext_vector_type(8))) short bf16x8;
typedef __attribute__((ext_vector_type(4))) float f32x4;

#define DEV static __device__ __forceinline__

DEV unsigned short f2bf(float f){
  union { float f; unsigned u; } v; v.f = f;
  unsigned r = v.u + 0x7fffu + ((v.u >> 16) & 1u);
  return (unsigned short)(r >> 16);
}
DEV float bf2f(unsigned short u){
  union { unsigned u; float f; } v; v.u = ((unsigned)u) << 16;
  return v.f;
}
DEV unsigned long long pk4(float a, float b, float c, float d){
  unsigned lo = (unsigned)f2bf(a) | ((unsigned)f2bf(b) << 16);
  unsigned hi = (unsigned)f2bf(c) | ((unsigned)f2bf(d) << 16);
  return ((unsigned long long)hi << 32) | lo;
}

// =============== prep-x: x convert/transpose + router only (gates the pipeline) ===============
__global__ __launch_bounds__(256) void k_prepx(const float* __restrict__ x,
                                               const float* __restrict__ Wr,
                                               const float* __restrict__ br,
                                               const float* __restrict__ bias0,
                                               unsigned short* __restrict__ xb,
                                               unsigned short* __restrict__ xT,
                                               float* __restrict__ routT){
  __shared__ float tile[64*65];
  __shared__ float lg[32][8];
  __shared__ float rt2[32][8];
  int bid = blockIdx.x;
  int t = threadIdx.x;
  if (bid < 256){                        // x: [2][2048][256] -> xb + xT
    int tx = t & 63, ty = t >> 6;        // 64 x 4
    int bat = bid >> 7, rem = bid & 127;
    int r0 = (rem >> 2) * 64, c0 = (rem & 3) * 64;
    size_t boff = (size_t)bat * 2048 * 256;
    for (int i = 0; i < 16; i++){
      float v = x[boff + (size_t)(r0 + ty + i*4) * 256 + c0 + tx];
      tile[(ty + i*4)*65 + tx] = v;
      xb[boff + (size_t)(r0 + ty + i*4) * 256 + c0 + tx] = f2bf(v);
    }
    __syncthreads();
    for (int i = 0; i < 16; i++)
      xT[(size_t)(bat*256 + c0 + ty + i*4) * 2048 + r0 + tx] = f2bf(tile[tx*65 + ty + i*4]);
  } else {                               // router: 128 blocks, 32 tokens each
    int row = t >> 3, mm = t & 7;
    int n = (bid - 256) * 32 + row;
    const float* xr = x + (size_t)n * 256;
    float acc = 0.f;
    for (int d = 0; d < 256; d++) acc += xr[d] * Wr[d * 8 + mm];
    acc += br[mm];
    lg[row][mm] = acc;
    __syncthreads();
    if (t < 32){
      int r = t; int n2 = (bid - 256) * 32 + r; int b = n2 >> 11;
      float mx = -1e30f;
      for (int i = 0; i < 8; i++) mx = fmaxf(mx, lg[r][i]);
      float s[8]; float sum = 0.f;
      for (int i = 0; i < 8; i++){ s[i] = __expf(lg[r][i] - mx); sum += s[i]; }
      for (int i = 0; i < 8; i++) s[i] /= sum;
      float bb[8];
      for (int i = 0; i < 8; i++) bb[i] = s[i] + bias0[b * 8 + i];
      int i1 = 0;
      for (int i = 1; i < 8; i++) if (bb[i] > bb[i1]) i1 = i;
      int i2 = -1;
      for (int i = 0; i < 8; i++){ if (i == i1) continue; if (i2 < 0 || bb[i] > bb[i2]) i2 = i; }
      float wsum = s[i1] + s[i2];
      for (int i = 0; i < 8; i++)
        rt2[r][i] = (i == i1) ? s[i1] / wsum : ((i == i2) ? s[i2] / wsum : 0.f);
    }
    __syncthreads();
    int n3 = (bid - 256) * 32 + row;
    int b = n3 >> 11, sl = n3 & 2047;
    routT[((size_t)b * 8 + mm) * 2048 + sl] = rt2[row][mm];
  }
}

// ====== MERGED: gpart (bid<128) + usum (128..255) + weight transposes (256..2559), 512 thr ======
__global__ __launch_bounds__(512) void k_gusum(const unsigned short* __restrict__ xT,
                                               const unsigned short* __restrict__ xb,
                                               const float* __restrict__ routT,
                                               const float* __restrict__ Wq,
                                               const float* __restrict__ Wk,
                                               const float* __restrict__ Wv,
                                               const float* __restrict__ Wo,
                                               unsigned short* __restrict__ Gp,
                                               float* __restrict__ upart,
                                               float* __restrict__ rhop,
                                               unsigned short* __restrict__ WkT,
                                               unsigned short* __restrict__ WvT,
                                               unsigned short* __restrict__ WoT,
                                               unsigned short* __restrict__ Wqb){
  __shared__ unsigned short As[256*72];
  __shared__ unsigned short Bs[256*72];
  __shared__ float rl[64];
  __shared__ float rl2[256];
  float* tile = (float*)As;                  // 64x65 f32 overlay (16.6 KB < 36 KB)
  int bid = blockIdx.x;
  int t = threadIdx.x;

  if (bid >= 256){
    int tx = t & 63, ty = t >> 6;            // 64 x 8
    if (bid < 2304){                         // Wk (256..1279) / Wv (1280..2303)
      const float* src = (bid < 1280) ? Wk : Wv;
      unsigned short* dst = (bid < 1280) ? WkT : WvT;
      int q = (bid < 1280) ? (bid - 256) : (bid - 1280);
      int bat = q >> 7, rem = q & 127;
      int c0 = (rem >> 2) * 64, r0 = (rem & 3) * 64;
      size_t boff = (size_t)bat * 256 * 2048;
      for (int i = 0; i < 8; i++)
        tile[(ty + i*8)*65 + tx] = src[boff + (size_t)(r0 + ty + i*8) * 2048 + c0 + tx];
      __syncthreads();
      for (int i = 0; i < 8; i++)
        dst[boff + (size_t)(c0 + ty + i*8) * 256 + r0 + tx] = f2bf(tile[tx*65 + ty + i*8]);
    } else if (bid < 2432){                  // Wo: [2048][256] -> [256][2048]
      int q = bid - 2304;
      int r0 = (q >> 2) * 64, c0 = (q & 3) * 64;
      for (int i = 0; i < 8; i++)
        tile[(ty + i*8)*65 + tx] = Wo[(size_t)(r0 + ty + i*8) * 256 + c0 + tx];
      __syncthreads();
      for (int i = 0; i < 8; i++)
        WoT[(size_t)(c0 + ty + i*8) * 2048 + r0 + tx] = f2bf(tile[tx*65 + ty + i*8]);
    } else {                                 // Wq plain convert [256][2048]: 128 blocks
      int q = bid - 2432;
      size_t idx = (size_t)q * 4096 + t * 8;
      f32x4 a = *(const f32x4*)(Wq + idx);
      f32x4 b = *(const f32x4*)(Wq + idx + 4);
      *(unsigned long long*)(Wqb + idx)     = pk4(a[0], a[1], a[2], a[3]);
      *(unsigned long long*)(Wqb + idx + 4) = pk4(b[0], b[1], b[2], b[3]);
    }
    return;
  }
  if (bid >= 128){
    // ---- usum: 128 blocks = bm(16) x scq(8); 512 threads = 2 halves of 128-token chunks
    int bid2 = bid - 128;
    int scq = bid2 & 7, bm = bid2 >> 3, b = bm >> 3;
    int half = t >> 8, td = t & 255;
    if (t < 256) rl2[t] = routT[(size_t)bm * 2048 + scq * 256 + t];
    __syncthreads();
    float acc = 0.f;
    const unsigned short* xrow = xb + ((size_t)(b * 2048 + scq * 256 + half * 128)) * 256 + td;
    const float* rlh = rl2 + half * 128;
    for (int s = 0; s < 128; s++){
      float rv = rlh[s];
      if (rv != 0.f)
        acc += rv * bf2f(xrow[(size_t)s * 256]);
    }
    upart[(size_t)(bm*16 + scq*2 + half) * 256 + td] = acc;
    if (td == 0){
      float rs = 0.f;
      for (int s = 0; s < 128; s++) rs += rlh[s];
      rhop[bm*16 + scq*2 + half] = rs;
    }
    return;
  }
  // ---- gpart: 128 blocks = b(2) m(8) kc(8)
  int kc = bid & 7, m = (bid >> 3) & 7, b = bid >> 6;
  int bm = b * 8 + m;
  int lane = t & 63, w = t >> 6;
  int li = lane & 15, lgp = lane >> 4;
  int p = w >> 2, q = w & 3;
  f32x4 acc[8][4];
  for (int i = 0; i < 8; i++) for (int j = 0; j < 4; j++) acc[i][j] = (f32x4){0,0,0,0};
  for (int c4 = 0; c4 < 4; c4++){
    int s0 = kc * 256 + c4 * 64;
    if (t < 64) rl[t] = routT[(size_t)bm*2048 + s0 + t];
    __syncthreads();
    for (int qq = 0; qq < 4; qq++){
      int idx = t + qq*512;
      int row = idx >> 3, sc = (idx & 7) * 8;
      bf16x8 xv = *(const bf16x8*)(xT + ((size_t)(b*256 + row))*2048 + s0 + sc);
      *(bf16x8*)(&Bs[row*72 + sc]) = xv;
      f32x4 r0 = *(const f32x4*)(rl + sc);
      f32x4 r1 = *(const f32x4*)(rl + sc + 4);
      bf16x8 sv;
      sv[0]=(short)f2bf(bf2f((unsigned short)xv[0])*r0[0]);
      sv[1]=(short)f2bf(bf2f((unsigned short)xv[1])*r0[1]);
      sv[2]=(short)f2bf(bf2f((unsigned short)xv[2])*r0[2]);
      sv[3]=(short)f2bf(bf2f((unsigned short)xv[3])*r0[3]);
      sv[4]=(short)f2bf(bf2f((unsigned short)xv[4])*r1[0]);
      sv[5]=(short)f2bf(bf2f((unsigned short)xv[5])*r1[1]);
      sv[6]=(short)f2bf(bf2f((unsigned short)xv[6])*r1[2]);
      sv[7]=(short)f2bf(bf2f((unsigned short)xv[7])*r1[3]);
      *(bf16x8*)(&As[row*72 + sc]) = sv;
    }
    __syncthreads();
    for (int kk = 0; kk < 2; kk++){
      bf16x8 Bf[4];
      for (int j = 0; j < 4; j++)
        Bf[j] = *(const bf16x8*)(&Bs[(q*64 + j*16 + li)*72 + kk*32 + lgp*8]);
      for (int i = 0; i < 8; i++){
        bf16x8 Af = *(const bf16x8*)(&As[(p*128 + i*16 + li)*72 + kk*32 + lgp*8]);
        for (int j = 0; j < 4; j++)
          acc[i][j] = __builtin_amdgcn_mfma_f32_16x16x32_bf16(Af, Bf[j], acc[i][j], 0, 0, 0);
      }
    }
    __syncthreads();
  }
  unsigned short* Cs = As;                   // 64 x 264 overlay
  for (int ph = 0; ph < 4; ph++){
    if (q == ph){
      for (int i = 0; i < 8; i++)
        for (int j = 0; j < 4; j++){
          int rr = j*16 + li, cc = p*128 + i*16 + lgp*4;
          *(unsigned long long*)(&Cs[rr*264 + cc]) =
            pk4(acc[i][j][0], acc[i][j][1], acc[i][j][2], acc[i][j][3]);
        }
    }
    __syncthreads();
    for (int qq = 0; qq < 4; qq++){
      int idx = t + qq*512;
      int row = idx >> 5, cc = (idx & 31) * 8;
      *(bf16x8*)(Gp + (((size_t)bm*8 + kc) << 16) + (size_t)(ph*64 + row)*256 + cc) =
        *(const bf16x8*)(&Cs[row*264 + cc]);
    }
    __syncthreads();
  }
}

// =============== MERGED: gred (bid<512) + bias (bid 512..639), 256 threads ===============
__global__ __launch_bounds__(256) void k_gbias(const unsigned short* __restrict__ Gp,
                                               const unsigned short* __restrict__ WkT,
                                               const unsigned short* __restrict__ WvT,
                                               const float* __restrict__ upart,
                                               const float* __restrict__ rhop,
                                               unsigned short* __restrict__ G,
                                               float* __restrict__ ku_g,
                                               float* __restrict__ vu_g,
                                               float* __restrict__ rho){
  __shared__ float uL[256];
  int bid = blockIdx.x;
  int t = threadIdx.x;
  if (bid < 512){
    int idx = bid * 256 + t;
    int bm = idx >> 13; size_t e8 = (size_t)(idx & 8191) * 8;
    float s[8] = {0,0,0,0,0,0,0,0};
    for (int kc = 0; kc < 8; kc++){
      bf16x8 v = *(const bf16x8*)(Gp + (((size_t)bm*8 + kc) << 16) + e8);
      for (int j = 0; j < 8; j++) s[j] += bf2f((unsigned short)v[j]);
    }
    *(unsigned long long*)(G + ((size_t)bm << 16) + e8)     = pk4(s[0], s[1], s[2], s[3]);
    *(unsigned long long*)(G + ((size_t)bm << 16) + e8 + 4) = pk4(s[4], s[5], s[6], s[7]);
    return;
  }
  int bid2 = bid - 512;
  int bm = bid2 >> 3, hseg = bid2 & 7, m = bm & 7;
  {
    float s = 0.f;
    for (int scn = 0; scn < 16; scn++)
      s += upart[(size_t)(bm*16 + scn) * 256 + t];
    uL[t] = s;
  }
  if (hseg == 0 && t == 0){
    float rs = 0.f;
    for (int scn = 0; scn < 16; scn++) rs += rhop[bm*16 + scn];
    rho[bm] = rs;
  }
  __syncthreads();
  int hd = hseg * 256 + t;
  const unsigned short* wk = WkT + ((size_t)m*2048 + hd) * 256;
  const unsigned short* wv = WvT + ((size_t)m*2048 + hd) * 256;
  float sk = 0.f, sv = 0.f;
  for (int d8 = 0; d8 < 256; d8 += 8){
    bf16x8 a = *(const bf16x8*)(wk + d8);
    bf16x8 c = *(const bf16x8*)(wv + d8);
    for (int j = 0; j < 8; j++){
      sk += bf2f((unsigned short)a[j]) * uL[d8+j];
      sv += bf2f((unsigned short)c[j]) * uL[d8+j];
    }
  }
  ku_g[(size_t)bm*2048 + hd] = sk;
  vu_g[(size_t)bm*2048 + hd] = sv;
}

// =============== Tt[bm][vd(hd) 2048][d1 256] = (G[bm] @ Wv_m)^T ===============
__global__ __launch_bounds__(512) void k_tmat(const unsigned short* __restrict__ G,
                                              const unsigned short* __restrict__ WvT,
                                              unsigned short* __restrict__ Tt){
  __shared__ unsigned short Cs[64*264];
  int bid = blockIdx.x;                         // 256 = bm(16) * hseg(16)
  int hseg = bid & 15, bm = bid >> 4, m = bm & 7;
  int t = threadIdx.x, lane = t & 63, w = t >> 6;
  int li = lane & 15, lgp = lane >> 4;
  int r = w >> 1, c = w & 1;
  f32x4 acc[4][4];
  for (int i = 0; i < 4; i++) for (int j = 0; j < 4; j++) acc[i][j] = (f32x4){0,0,0,0};
  const unsigned short* gp = G + ((size_t)bm << 16) + (size_t)(r*64 + li)*256 + lgp*8;
  const unsigned short* wp = WvT + ((size_t)m*2048 + hseg*128 + c*64 + li)*256 + lgp*8;
  #pragma unroll
  for (int kk = 0; kk < 8; kk++){
    bf16x8 Bf[4];
    for (int j = 0; j < 4; j++)
      Bf[j] = *(const bf16x8*)(wp + (size_t)(j*16)*256 + kk*32);
    for (int i = 0; i < 4; i++){
      bf16x8 Af = *(const bf16x8*)(gp + (size_t)(i*16)*256 + kk*32);
      for (int j = 0; j < 4; j++)
        acc[i][j] = __builtin_amdgcn_mfma_f32_16x16x32_bf16(Af, Bf[j], acc[i][j], 0, 0, 0);
    }
  }
  for (int ph = 0; ph < 2; ph++){
    if (c == ph){
      for (int i = 0; i < 4; i++)
        for (int j = 0; j < 4; j++)
          *(unsigned long long*)(&Cs[(j*16 + li)*264 + r*64 + i*16 + lgp*4]) =
            pk4(acc[i][j][0], acc[i][j][1], acc[i][j][2], acc[i][j][3]);
    }
    __syncthreads();
    for (int q = 0; q < 4; q++){
      int idx = t + q*512;
      int row = idx >> 5, cc = (idx & 31) * 8;
      *(bf16x8*)(Tt + ((size_t)bm*2048 + hseg*128 + ph*64 + row)*256 + cc) =
        *(const bf16x8*)(&Cs[row*264 + cc]);
    }
    __syncthreads();
  }
}

// =============== mempartB[m][h][vq][kq][b] (128x128 bf16) = Tt_m x WkT_m ===============
__global__ __launch_bounds__(512) void k_kmat3(const unsigned short* __restrict__ Tt,
                                               const unsigned short* __restrict__ WkT,
                                               unsigned short* __restrict__ mempartB){
  int bid = blockIdx.x;                         // 256 = h(8) vq(2) kq(2) m(8)
  int m = bid & 7, kq = (bid >> 3) & 1, vq = (bid >> 4) & 1, h = bid >> 5;
  int hd0 = h * 256;
  int t = threadIdx.x, lane = t & 63, w = t >> 6;
  int li = lane & 15, lgp = lane >> 4;
  int wr = w >> 2, wc = w & 3;
  f32x4 acc[2][2][4];
  for (int b = 0; b < 2; b++)
    for (int i = 0; i < 2; i++)
      for (int j = 0; j < 4; j++) acc[b][i][j] = (f32x4){0,0,0,0};
  const unsigned short* ap  = WkT + ((size_t)m*2048 + hd0 + kq*128 + wc*32 + li)*256 + lgp*8;
  const unsigned short* bp0 = Tt + ((size_t)(m)*2048 + hd0 + vq*128 + wr*64 + li)*256 + lgp*8;
  const unsigned short* bp1 = Tt + ((size_t)(8 + m)*2048 + hd0 + vq*128 + wr*64 + li)*256 + lgp*8;
  #pragma unroll
  for (int kk = 0; kk < 8; kk++){
    bf16x8 Af[2], B0[4], B1[4];
    Af[0] = *(const bf16x8*)(ap + kk*32);
    Af[1] = *(const bf16x8*)(ap + 16*256 + kk*32);
    for (int j = 0; j < 4; j++){
      B0[j] = *(const bf16x8*)(bp0 + (size_t)(j*16)*256 + kk*32);
      B1[j] = *(const bf16x8*)(bp1 + (size_t)(j*16)*256 + kk*32);
    }
    for (int i = 0; i < 2; i++)
      for (int j = 0; j < 4; j++){
        acc[0][i][j] = __builtin_amdgcn_mfma_f32_16x16x32_bf16(Af[i], B0[j], acc[0][i][j], 0, 0, 0);
        acc[1][i][j] = __builtin_amdgcn_mfma_f32_16x16x32_bf16(Af[i], B1[j], acc[1][i][j], 0, 0, 0);
      }
  }
  for (int b = 0; b < 2; b++){
    unsigned short* Fp = mempartB + ((((((size_t)m*8 + h)*2 + vq)*2 + kq)*2 + b)) * 16384;
    for (int j = 0; j < 4; j++){
      int vdt = wr*64 + j*16 + li;
      for (int i = 0; i < 2; i++){
        int kdt = wc*32 + i*16 + lgp*4;
        *(unsigned long long*)(Fp + (size_t)vdt*128 + kdt) =
          pk4(acc[b][i][j][0], acc[b][i][j][1], acc[b][i][j][2], acc[b][i][j][3]);
      }
    }
  }
}

// =============== k_kred: memT[bh][vd][kd] = Sum_m mempartB + rank-1 epilogue ===============
__global__ __launch_bounds__(256) void k_kred(const unsigned short* __restrict__ mempartB,
                                              const float* __restrict__ bk,
                                              const float* __restrict__ bv,
                                              const float* __restrict__ ku_g,
                                              const float* __restrict__ vu_g,
                                              const float* __restrict__ rho,
                                              unsigned short* __restrict__ memT){
  int idx = blockIdx.x * 256 + threadIdx.x;     // 262144
  int bh = idx >> 14;
  int rem = idx & 16383;
  int vd = rem >> 6, kd = (rem & 63) * 4;
  int b = bh >> 3, h = bh & 7;
  int vdg = h*256 + vd, kdg = h*256 + kd;
  int vq = vd >> 7, kq = kd >> 7;
  size_t src = ((((size_t)h*2 + vq)*2 + kq)*2 + b) * 16384 + (size_t)(vd & 127)*128 + (kd & 127);
  f32x4 s = (f32x4){0,0,0,0};
  #pragma unroll
  for (int m = 0; m < 8; m++){
    unsigned long long v = *(const unsigned long long*)(mempartB + (size_t)m*1048576 + src);
    s[0] += bf2f((unsigned short)v);
    s[1] += bf2f((unsigned short)(v >> 16));
    s[2] += bf2f((unsigned short)(v >> 32));
    s[3] += bf2f((unsigned short)(v >> 48));
  }
  #pragma unroll
  for (int m = 0; m < 8; m++){
    float bvv = bv[(size_t)m*2048 + vdg];
    float bb  = vu_g[(size_t)(b*8+m)*2048 + vdg] + rho[b*8+m]*bvv;
    f32x4 ku4 = *(const f32x4*)(ku_g + (size_t)(b*8+m)*2048 + kdg);
    f32x4 bk4 = *(const f32x4*)(bk + (size_t)m*2048 + kdg);
    s[0] += ku4[0]*bvv + bk4[0]*bb;
    s[1] += ku4[1]*bvv + bk4[1]*bb;
    s[2] += ku4[2]*bvv + bk4[2]*bb;
    s[3] += ku4[3]*bvv + bk4[3]*bb;
  }
  *(unsigned long long*)(memT + (size_t)bh*65536 + (size_t)vd*256 + kd) =
    pk4(s[0], s[1], s[2], s[3]);
}

// =============== E_h = Wq_h @ mem_h -> Eb; qbAll = bq_h . mem_h ===============
__global__ __launch_bounds__(512) void k_emat(const unsigned short* __restrict__ memT,
                                              const unsigned short* __restrict__ Wqb,
                                              const float* __restrict__ bq,
                                              unsigned short* __restrict__ Eb,
                                              float* __restrict__ qbAll){
  __shared__ unsigned short Cs[16*264];
  int bid = blockIdx.x;                        // 64 = bh(16) * dseg(4)
  int dseg = bid & 3, bh = bid >> 2;
  int b = bh >> 3, h = bh & 7;
  int hd0 = h * 256, d0 = dseg * 64;
  int t = threadIdx.x, lane = t & 63, w = t >> 6;
  int li = lane & 15, lgp = lane >> 4;
  int r = w >> 2, c = w & 3;
  f32x4 acc[8];
  for (int i = 0; i < 8; i++) acc[i] = (f32x4){0,0,0,0};
  for (int kk = 0; kk < 8; kk++){
    bf16x8 Bf = *(const bf16x8*)(Wqb + (size_t)(d0 + c*16 + li)*2048 + hd0 + kk*32 + lgp*8);
    for (int i = 0; i < 8; i++){
      bf16x8 Af = *(const bf16x8*)(memT + (size_t)bh*65536 + (size_t)(r*128 + i*16 + li)*256 + kk*32 + lgp*8);
      acc[i] = __builtin_amdgcn_mfma_f32_16x16x32_bf16(Af, Bf, acc[i], 0, 0, 0);
    }
  }
  if (dseg == 0 && t < 256){
    const unsigned short* mrow = memT + (size_t)bh*65536 + (size_t)t*256;
    float s = 0.f;
    for (int k8 = 0; k8 < 256; k8 += 8){
      bf16x8 v = *(const bf16x8*)(mrow + k8);
      for (int e = 0; e < 8; e++) s += bf2f((unsigned short)v[e]) * bq[hd0 + k8 + e];
    }
    qbAll[(size_t)b*2048 + hd0 + t] = s;
  }
  for (int ph = 0; ph < 4; ph++){
    if (c == ph){
      for (int i = 0; i < 8; i++)
        *(unsigned long long*)(&Cs[li*264 + r*128 + i*16 + lgp*4]) =
          pk4(acc[i][0], acc[i][1], acc[i][2], acc[i][3]);
    }
    __syncthreads();
    {
      int row = t >> 5, cc = (t & 31) * 8;
      *(bf16x8*)(Eb + (size_t)b*524288 + (size_t)(d0 + ph*16 + row)*2048 + hd0 + cc) =
        *(const bf16x8*)(&Cs[row*264 + cc]);
    }
    __syncthreads();
  }
}

// =============== Fpart = Eb x Wo slice-K (split-K 8); tail: c0 ===============
__global__ __launch_bounds__(512) void k_fmat(const unsigned short* __restrict__ Eb,
                                              const unsigned short* __restrict__ WoT,
                                              const float* __restrict__ qbAll,
                                              const float* __restrict__ bo,
                                              float* __restrict__ Fpart,
                                              float* __restrict__ c0acc){
  __shared__ float qL[2048];
  int bid = blockIdx.x;
  int t = threadIdx.x;
  if (bid >= 256){
    int b = bid - 256;
    for (int i = t; i < 2048; i += 512) qL[i] = qbAll[(size_t)b * 2048 + i];
    __syncthreads();
    int w = t >> 6, lane = t & 63;
    for (int dd = w; dd < 256; dd += 8){
      const unsigned short* wrow = WoT + (size_t)dd * 2048 + lane * 8;
      const float* qp = qL + lane * 8;
      float s = 0.f;
      for (int pass = 0; pass < 4; pass++){
        bf16x8 v = *(const bf16x8*)(wrow + pass * 512);
        const float* q = qp + pass * 512;
        for (int e = 0; e < 8; e++) s += bf2f((unsigned short)v[e]) * q[e];
      }
      for (int off = 32; off; off >>= 1) s += __shfl_down(s, off);
      if (lane == 0) c0acc[(size_t)b * 256 + dd] = s + bo[dd];
    }
    return;
  }
  int ks = bid & 7, dseg = (bid >> 3) & 3, doseg = (bid >> 5) & 3, b = bid >> 7;
  int do0 = doseg * 64, d0 = dseg * 64, k0 = ks * 256;
  int lane = t & 63, w = t >> 6;
  int li = lane & 15, lgp = lane >> 4;
  int r = w >> 2, c = w & 3;
  f32x4 acc[2];
  acc[0] = (f32x4){0,0,0,0}; acc[1] = (f32x4){0,0,0,0};
  const unsigned short* bp = Eb + (size_t)b*524288 + (size_t)(d0 + c*16 + li)*2048 + k0 + lgp*8;
  const unsigned short* ap = WoT + (size_t)(do0 + r*32 + li)*2048 + k0 + lgp*8;
  #pragma unroll
  for (int kk = 0; kk < 8; kk++){
    bf16x8 Bf = *(const bf16x8*)(bp + kk*32);
    bf16x8 Af0 = *(const bf16x8*)(ap + kk*32);
    bf16x8 Af1 = *(const bf16x8*)(ap + kk*32 + 16*2048);
    acc[0] = __builtin_amdgcn_mfma_f32_16x16x32_bf16(Af0, Bf, acc[0], 0, 0, 0);
    acc[1] = __builtin_amdgcn_mfma_f32_16x16x32_bf16(Af1, Bf, acc[1], 0, 0, 0);
  }
  int dd = d0 + c*16 + li;
  float* Fp = Fpart + ((size_t)(ks*2 + b)) * 65536;
  for (int i = 0; i < 2; i++){
    int dor = do0 + r*32 + i*16 + lgp*4;
    float* p = Fp + (size_t)dor*256 + dd;
    p[0]   = acc[i][0];
    p[256] = acc[i][1];
    p[512] = acc[i][2];
    p[768] = acc[i][3];
  }
}

// =============== reduce Fpart over ks -> Fb ===============
__global__ __launch_bounds__(256) void k_fred(const float* __restrict__ Fpart,
                                              unsigned short* __restrict__ Fb){
  int idx = blockIdx.x * 256 + threadIdx.x;
  int b = idx >> 14; int e4 = (idx & 16383) * 4;
  f32x4 s = (f32x4){0,0,0,0};
  for (int ks = 0; ks < 8; ks++){
    f32x4 v = *(const f32x4*)(Fpart + ((size_t)(ks*2 + b)) * 65536 + e4);
    s[0] += v[0]; s[1] += v[1]; s[2] += v[2]; s[3] += v[3];
  }
  *(unsigned long long*)(Fb + (size_t)b*65536 + e4) = pk4(s[0], s[1], s[2], s[3]);
}

// =============== out[tok][do] = x @ F(bf16) + c0 ===============
__global__ __launch_bounds__(512) void k_final2(const unsigned short* __restrict__ Fb,
                                                const unsigned short* __restrict__ xb,
                                                const float* __restrict__ c0acc,
                                                float* __restrict__ out){
  int bid = blockIdx.x;                        // 64 = b(2) * tc(32)
  int tc = bid & 31, b = bid >> 5;
  int t = threadIdx.x, lane = t & 63, w = t >> 6;
  int li = lane & 15, lgp = lane >> 4;
  int r = w >> 1, c = w & 1;
  int tok0 = b * 2048 + tc * 64;
  f32x4 acc[4][2];
  for (int i = 0; i < 4; i++) for (int j = 0; j < 2; j++) acc[i][j] = (f32x4){0,0,0,0};
  for (int kk = 0; kk < 8; kk++){
    bf16x8 Bf[2];
    for (int j = 0; j < 2; j++)
      Bf[j] = *(const bf16x8*)(xb + (size_t)(tok0 + c*32 + j*16 + li)*256 + kk*32 + lgp*8);
    for (int i = 0; i < 4; i++){
      bf16x8 af = *(const bf16x8*)(Fb + (size_t)b*65536 + (size_t)(r*64 + i*16 + li)*256 + kk*32 + lgp*8);
      for (int j = 0; j < 2; j++)
        acc[i][j] = __builtin_amdgcn_mfma_f32_16x16x32_bf16(af, Bf[j], acc[i][j], 0, 0, 0);
    }
  }
  for (int i = 0; i < 4; i++){
    int dol = r*64 + i*16 + lgp*4;
    f32x4 c4 = *(const f32x4*)(c0acc + (size_t)b*256 + dol);
    for (int j = 0; j < 2; j++){
      int tokl = c*32 + j*16 + li;
      f32x4 v = acc[i][j];
      v[0] += c4[0]; v[1] += c4[1]; v[2] += c4[2]; v[3] += c4[3];
      *(f32x4*)(out + (size_t)(tok0 + tokl)*256 + dol) = v;
    }
  }
}

extern "C" void kernel_launch(void* const* d_in, const int* in_sizes, int n_in,
                              void* d_out, int out_size, void* d_ws, size_t ws_size,
                              hipStream_t stream) {
  const float* x     = (const float*)d_in[0];
  const float* Wq    = (const float*)d_in[1];
  const float* bq    = (const float*)d_in[2];
  const float* Wr    = (const float*)d_in[3];
  const float* br    = (const float*)d_in[4];
  const float* Wk    = (const float*)d_in[5];
  const float* bk    = (const float*)d_in[6];
  const float* Wv    = (const float*)d_in[7];
  const float* bv    = (const float*)d_in[8];
  const float* Wo    = (const float*)d_in[9];
  const float* bo    = (const float*)d_in[10];
  const float* bias0 = (const float*)d_in[11];
  float* out = (float*)d_out;

  char* ws = (char*)d_ws;
  size_t off = 0;
  auto alloc = [&](size_t bytes) -> char* {
    char* p = ws + off;
    off = (off + bytes + 255) & ~(size_t)255;
    return p;
  };
  unsigned short* xb   = (unsigned short*)alloc((size_t)4096 * 256 * 2);      // 2 MB
  unsigned short* xT   = (unsigned short*)alloc((size_t)2 * 256 * 2048 * 2);  // 2 MB
  unsigned short* Wqb  = (unsigned short*)alloc((size_t)256 * 2048 * 2);      // 1 MB
  unsigned short* WkT  = (unsigned short*)alloc((size_t)8 * 2048 * 256 * 2);  // 8 MB
  unsigned short* WvT  = (unsigned short*)alloc((size_t)8 * 2048 * 256 * 2);  // 8 MB
  unsigned short* WoT  = (unsigned short*)alloc((size_t)256 * 2048 * 2);      // 1 MB
  float*          routT= (float*)alloc((size_t)16 * 2048 * 4);                // 128 KB
  float*          upart= (float*)alloc((size_t)256 * 256 * 4);                // 256 KB
  float*          rhop = (float*)alloc((size_t)256 * 4);
  float*          rho  = (float*)alloc((size_t)16 * 4);
  float*          ku_g = (float*)alloc((size_t)16 * 2048 * 4);
  float*          vu_g = (float*)alloc((size_t)16 * 2048 * 4);
  unsigned short* Gp   = (unsigned short*)alloc((size_t)16 * 8 * 65536 * 2);  // 16 MB
  unsigned short* G    = (unsigned short*)alloc((size_t)16 * 65536 * 2);      // 2 MB
  unsigned short* memT = (unsigned short*)alloc((size_t)16 * 65536 * 2);      // 2 MB
  unsigned short* Eb   = (unsigned short*)alloc((size_t)2 * 256 * 2048 * 2);  // 2 MB
  float*          qbAll= (float*)alloc((size_t)2 * 2048 * 4);
  float*          Fpart= (float*)alloc((size_t)16 * 65536 * 4);               // 4 MB
  unsigned short* Fb   = (unsigned short*)alloc((size_t)2 * 65536 * 2);       // 256 KB
  float*          c0acc= (float*)alloc((size_t)2 * 256 * 4);
  unsigned short* mempartB = (unsigned short*)alloc((size_t)8 * 1048576 * 2); // 16 MB
  unsigned short* Tt   = Gp;      // alias: Gp dead after k_gbias(gred part)
  (void)ws_size; (void)in_sizes; (void)n_in; (void)out_size;

  k_prepx<<<384, 256, 0, stream>>>(x, Wr, br, bias0, xb, xT, routT);
  k_gusum<<<2560, 512, 0, stream>>>(xT, xb, routT, Wq, Wk, Wv, Wo,
                                    Gp, upart, rhop, WkT, WvT, WoT, Wqb);
  k_gbias<<<640, 256, 0, stream>>>(Gp, WkT, WvT, upart, rhop, G, ku_g, vu_g, rho);
  k_tmat<<<256, 512, 0, stream>>>(G, WvT, Tt);
  k_kmat3<<<256, 512, 0, stream>>>(Tt, WkT, mempartB);
  k_kred<<<1024, 256, 0, stream>>>(mempartB, bk, bv, ku_g, vu_g, rho, memT);
  k_emat<<<64, 512, 0, stream>>>(memT, Wqb, bq, Eb, qbAll);
  k_fmat<<<258, 512, 0, stream>>>(Eb, WoT, qbAll, bo, Fpart, c0acc);
  k_fred<<<128, 256, 0, stream>>>(Fpart, Fb);
  k_final2<<<64, 512, 0, stream>>>(Fb, xb, c0acc, out);
}